// Round 4
// baseline (2096.331 us; speedup 1.0000x reference)
//
#include <hip/hip_runtime.h>
#include <hip/hip_bf16.h>
#include <math.h>

#define N_NODES 50000
#define N_EDGES 800000
#define HID 128
#define NF 128
#define C3 384   // 3*H
#define SILU_SCALE (1.0f/0.6f)
#define INV_SQRT3 0.57735026918962576f
#define INV_SQRTH 0.08838834764831845f   // 1/sqrt(128)

// max groups: sum ceil(d/16) <= E/16 + N*15/16 = 50000 + 46875 = 96875
#define GMAX 96880            // padded to multiple of 4 (waves per block)
#define GBLOCKS (GMAX / 4)    // 24220
#define PERM_SLOTS (GMAX * 16)

typedef __bf16 bf16x8 __attribute__((ext_vector_type(8)));
typedef __bf16 bf16x4 __attribute__((ext_vector_type(4)));
typedef float  floatx4 __attribute__((ext_vector_type(4)));

// ---------------------------------------------------------------------------
// Cast + transpose We [128][384] f32 -> WeT [384][128] bf16
// ---------------------------------------------------------------------------
__global__ void cast_weT(const float* __restrict__ We, __bf16* __restrict__ WeT) {
    int o = blockIdx.x * 256 + threadIdx.x;   // 49152 total
    int n = o / NF, k = o % NF;
    WeT[o] = (__bf16)We[k * C3 + n];
}

// ---------------------------------------------------------------------------
// vec f32 [N,3,128] -> bf16 (gather side stays L3-resident: 38.4 MB)
// ---------------------------------------------------------------------------
__global__ void cast_vec(const float* __restrict__ v, __bf16* __restrict__ vb) {
    int o = blockIdx.x * 256 + threadIdx.x;   // float4 granule, 4.8M total
    float4 u = ((const float4*)v)[o];
    bf16x4 b;
    b[0] = (__bf16)u.x; b[1] = (__bf16)u.y; b[2] = (__bf16)u.z; b[3] = (__bf16)u.w;
    ((bf16x4*)vb)[o] = b;
}

// ---------------------------------------------------------------------------
// Node MLP: x_h = (silu(x@W1+b1)*SILU_SCALE) @ W2 + b2, output bf16.
// ---------------------------------------------------------------------------
__global__ __launch_bounds__(384)
void node_mlp(const float* __restrict__ x,  const float* __restrict__ W1,
              const float* __restrict__ b1, const float* __restrict__ W2,
              const float* __restrict__ b2, __bf16* __restrict__ x_hb) {
    __shared__ float xs[16][HID];   // 8 KB
    __shared__ float hs[16][64];    // 4 KB
    const int t = threadIdx.x;
    const int base = blockIdx.x * 16;

    for (int f4 = t; f4 < 512; f4 += 384) {   // 16*128 floats = 512 float4
        float4 v = ((const float4*)(x + (size_t)base * HID))[f4];
        ((float4*)&xs[0][0])[f4] = v;
    }
    __syncthreads();
    for (int o = t; o < 1024; o += 384) {     // 16 nodes x 64 mid
        int g = o >> 6, m = o & 63;
        float sum = b1[m];
        #pragma unroll 8
        for (int k = 0; k < HID; ++k) sum += xs[g][k] * W1[k * 64 + m];
        float sig = 1.0f / (1.0f + __expf(-sum));
        hs[g][m] = sum * sig * SILU_SCALE;
    }
    __syncthreads();
    {
        float acc[16];
        #pragma unroll
        for (int n = 0; n < 16; ++n) acc[n] = b2[t];
        for (int k = 0; k < 64; ++k) {
            float w2 = W2[k * C3 + t];
            #pragma unroll
            for (int n = 0; n < 16; ++n) acc[n] += hs[n][k] * w2;
        }
        #pragma unroll
        for (int n = 0; n < 16; ++n) x_hb[(size_t)(base + n) * C3 + t] = (__bf16)acc[n];
    }
}

// ---------------------------------------------------------------------------
// CSR build: histogram -> scan -> parallel table fill -> scatter
// ---------------------------------------------------------------------------
__global__ void hist_k(const int* __restrict__ eidx, int* __restrict__ counts) {
    int e = blockIdx.x * 256 + threadIdx.x;
    if (e < N_EDGES) atomicAdd(&counts[eidx[N_EDGES + e]], 1);
}

__global__ __launch_bounds__(1024)
void scan_k(const int* __restrict__ counts, int* __restrict__ first_group,
            int* __restrict__ G_total) {
    __shared__ int ls[1024];
    const int t = threadIdx.x;
    const int CH = 49;                 // 1024*49 = 50176 >= 50000
    const int base = t * CH;
    int s = 0;
    for (int k = 0; k < CH; ++k) {
        int i = base + k;
        if (i < N_NODES) s += (counts[i] + 15) >> 4;
    }
    ls[t] = s;
    __syncthreads();
    for (int off = 1; off < 1024; off <<= 1) {   // Hillis-Steele inclusive
        int v = (t >= off) ? ls[t - off] : 0;
        __syncthreads();
        ls[t] += v;
        __syncthreads();
    }
    if (t == 1023) *G_total = ls[1023];
    int run = (t == 0) ? 0 : ls[t - 1];
    for (int k = 0; k < CH; ++k) {
        int i = base + k;
        if (i < N_NODES) {
            first_group[i] = run;
            run += (counts[i] + 15) >> 4;
        }
    }
}

__global__ void fill_k(const int* __restrict__ counts,
                       const int* __restrict__ first_group,
                       int* __restrict__ group_node, int* __restrict__ group_valid) {
    int i = blockIdx.x * 256 + threadIdx.x;
    if (i >= N_NODES) return;
    int d = counts[i], fg = first_group[i], ng = (d + 15) >> 4;
    for (int q = 0; q < ng; ++q) {
        group_node[fg + q]  = i;
        int rem = d - 16 * q;
        group_valid[fg + q] = rem > 16 ? 16 : rem;
    }
}

__global__ void scatter_k(const int* __restrict__ eidx,
                          const int* __restrict__ first_group,
                          int* __restrict__ cursor, int* __restrict__ perm) {
    int e = blockIdx.x * 256 + threadIdx.x;
    if (e >= N_EDGES) return;
    int i = eidx[N_EDGES + e];
    int pos = atomicAdd(&cursor[i], 1);
    perm[first_group[i] * 16 + pos] = e;
}

// ---------------------------------------------------------------------------
// Fused edge kernel, TRANSPOSED MFMA mapping. One wave = one group = 16 edges
// with one destination node. A-operand = WeT rows (M = 16 columns), B-operand
// = gathered rbf rows (N = 16 edges). C/D: lane&15 = edge, quad*4+r = column
// -> each lane owns ONE edge and 4 CONSECUTIVE columns, so x_h/vec gathers
// are 8B-vector loads (16 cachelines per instruction of MLP). No LDS, no
// barriers. Edge reduction = 4-stage shfl_xor butterfly over the 16 er lanes.
// ---------------------------------------------------------------------------
__global__ __launch_bounds__(256)
void edge_kernel(const float* __restrict__ edge_rbf,
                 const __bf16* __restrict__ WeT,
                 const float* __restrict__ be,
                 const __bf16* __restrict__ x_hb,
                 const __bf16* __restrict__ vecb,
                 const float* __restrict__ edge_vector,
                 const int*   __restrict__ eidx,
                 const int*   __restrict__ perm,
                 const int*   __restrict__ group_node,
                 const int*   __restrict__ group_valid,
                 const int*   __restrict__ G_total,
                 float* __restrict__ d_x, float* __restrict__ d_vec) {
    const int t = threadIdx.x;
    const int w = t >> 6, l = t & 63;
    const int er = l & 15, quad = l >> 4;
    const int g = blockIdx.x * 4 + w;
    if (g >= *G_total) return;

    const int i_node = group_node[g];
    const int nval   = group_valid[g];
    const int e      = perm[(size_t)g * 16 + er];   // this lane's edge
    const int j      = eidx[e];
    const float ev0  = edge_vector[(size_t)e * 3 + 0];
    const float ev1  = edge_vector[(size_t)e * 3 + 1];
    const float ev2  = edge_vector[(size_t)e * 3 + 2];
    const float sA   = (er < nval) ? INV_SQRT3 : 0.f;
    const float sB   = sA * INV_SQRTH;

    // B-frags: edge er's rbf row, k = s*32 + quad*8 + j, f32 -> bf16 in-reg
    bf16x8 bfrag[4];
    const float* rp = edge_rbf + (size_t)e * NF + quad * 8;
    #pragma unroll
    for (int s = 0; s < 4; ++s) {
        const float4 u0 = *(const float4*)(rp + s * 32);
        const float4 u1 = *(const float4*)(rp + s * 32 + 4);
        bf16x8 b;
        b[0] = (__bf16)u0.x; b[1] = (__bf16)u0.y; b[2] = (__bf16)u0.z; b[3] = (__bf16)u0.w;
        b[4] = (__bf16)u1.x; b[5] = (__bf16)u1.y; b[6] = (__bf16)u1.z; b[7] = (__bf16)u1.w;
        bfrag[s] = b;
    }

    const __bf16* xh = x_hb + (size_t)j * C3;
    const __bf16* vj = vecb + (size_t)j * C3;
    float* dxp = d_x  + (size_t)i_node * HID;
    float* dvp = d_vec + (size_t)i_node * 3 * HID;

    #pragma unroll
    for (int ct = 0; ct < 8; ++ct) {
        floatx4 a1 = (floatx4){0.f,0.f,0.f,0.f};
        floatx4 a2 = (floatx4){0.f,0.f,0.f,0.f};
        floatx4 a3 = (floatx4){0.f,0.f,0.f,0.f};
        const __bf16* wp = WeT + (size_t)(16 * ct + er) * NF + quad * 8;
        #pragma unroll
        for (int s = 0; s < 4; ++s) {
            a1 = __builtin_amdgcn_mfma_f32_16x16x32_bf16(*(const bf16x8*)(wp + s * 32),            bfrag[s], a1, 0, 0, 0);
            a2 = __builtin_amdgcn_mfma_f32_16x16x32_bf16(*(const bf16x8*)(wp + 128 * NF + s * 32), bfrag[s], a2, 0, 0, 0);
            a3 = __builtin_amdgcn_mfma_f32_16x16x32_bf16(*(const bf16x8*)(wp + 256 * NF + s * 32), bfrag[s], a3, 0, 0, 0);
        }
        const int c0 = ct * 16 + quad * 4;
        const bf16x4 xh1 = *(const bf16x4*)(xh + c0);
        const bf16x4 xh2 = *(const bf16x4*)(xh + 128 + c0);
        const bf16x4 xh3 = *(const bf16x4*)(xh + 256 + c0);
        const bf16x4 vj0 = *(const bf16x4*)(vj + c0);
        const bf16x4 vj1 = *(const bf16x4*)(vj + 128 + c0);
        const bf16x4 vj2 = *(const bf16x4*)(vj + 256 + c0);
        const float4 be1 = *(const float4*)(be + c0);
        const float4 be2 = *(const float4*)(be + 128 + c0);
        const float4 be3 = *(const float4*)(be + 256 + c0);
        float q0[4], q1[4], q2[4], q3[4];
        const float* be1p = (const float*)&be1;
        const float* be2p = (const float*)&be2;
        const float* be3p = (const float*)&be3;
        #pragma unroll
        for (int r = 0; r < 4; ++r) {
            const float rbf1 = a1[r] + be1p[r];
            const float rbf2 = a2[r] + be2p[r];
            const float rbf3 = a3[r] + be3p[r];
            const float x1 = (float)xh1[r] * rbf1 * sB;
            const float x2 = (float)xh2[r] * rbf2 * sB;
            const float x3 = (float)xh3[r] * rbf3 * sA;
            q0[r] = x3;
            q1[r] = x1 * (float)vj0[r] + x2 * ev0;
            q2[r] = x1 * (float)vj1[r] + x2 * ev1;
            q3[r] = x1 * (float)vj2[r] + x2 * ev2;
        }
        // reduce over the 16 er-lanes (edges); quad bits untouched
        #pragma unroll
        for (int m = 1; m <= 8; m <<= 1) {
            #pragma unroll
            for (int r = 0; r < 4; ++r) {
                q0[r] += __shfl_xor(q0[r], m);
                q1[r] += __shfl_xor(q1[r], m);
                q2[r] += __shfl_xor(q2[r], m);
                q3[r] += __shfl_xor(q3[r], m);
            }
        }
        if (er < 4) {
            float* bp = (er == 0) ? (dxp + c0) : (dvp + (er - 1) * HID + c0);
            #pragma unroll
            for (int r = 0; r < 4; ++r) {
                const float v = (er == 0) ? q0[r] : (er == 1) ? q1[r]
                              : (er == 2) ? q2[r] : q3[r];
                unsafeAtomicAdd(bp + r, v);
            }
        }
    }
}

// ---------------------------------------------------------------------------
extern "C" void kernel_launch(void* const* d_in, const int* in_sizes, int n_in,
                              void* d_out, int out_size, void* d_ws, size_t ws_size,
                              hipStream_t stream) {
    const float* x    = (const float*)d_in[0];
    const float* vec  = (const float*)d_in[1];
    const float* erbf = (const float*)d_in[2];
    const float* evec = (const float*)d_in[3];
    const int*   eidx = (const int*)d_in[4];
    const float* W1   = (const float*)d_in[5];
    const float* b1   = (const float*)d_in[6];
    const float* W2   = (const float*)d_in[7];
    const float* b2   = (const float*)d_in[8];
    const float* We   = (const float*)d_in[9];
    const float* be   = (const float*)d_in[10];

    float* out   = (float*)d_out;
    float* d_x   = out;                              // [N, H]
    float* d_vec = out + (size_t)N_NODES * HID;      // [N, 3, H]

    // ---- workspace layout ----
    char* p = (char*)d_ws;
    __bf16* x_hb       = (__bf16*)p; p += (size_t)N_NODES * C3 * 2;     // 38.4 MB
    __bf16* vecb       = (__bf16*)p; p += (size_t)N_NODES * C3 * 2;     // 38.4 MB
    __bf16* WeT        = (__bf16*)p; p += (size_t)C3 * NF * 2;          // 96 KB
    int* first_group   = (int*)p;    p += 50176 * 4;
    int* group_node    = (int*)p;    p += (GMAX + 16) * 4;
    int* group_valid   = (int*)p;    p += (GMAX + 16) * 4;
    int* G_total       = (int*)p;    p += 256;
    // zero-initialized region: counts, cursor, perm (one memset)
    char* zbase        = p;
    int* counts        = (int*)p;    p += 50176 * 4;
    int* cursor        = (int*)p;    p += 50176 * 4;
    int* perm          = (int*)p;    p += (size_t)PERM_SLOTS * 4;       // 6.2 MB
    size_t zbytes      = (size_t)(p - zbase);

    hipMemsetAsync(zbase, 0, zbytes, stream);
    hipMemsetAsync(d_out, 0, (size_t)out_size * sizeof(float), stream);

    cast_weT<<<(C3 * NF) / 256, 256, 0, stream>>>(We, WeT);
    cast_vec<<<(N_NODES * 3 * HID / 4) / 256, 256, 0, stream>>>(vec, vecb);
    node_mlp<<<N_NODES / 16, 384, 0, stream>>>(x, W1, b1, W2, b2, x_hb);
    hist_k<<<(N_EDGES + 255) / 256, 256, 0, stream>>>(eidx, counts);
    scan_k<<<1, 1024, 0, stream>>>(counts, first_group, G_total);
    fill_k<<<(N_NODES + 255) / 256, 256, 0, stream>>>(counts, first_group,
                                                      group_node, group_valid);
    scatter_k<<<(N_EDGES + 255) / 256, 256, 0, stream>>>(eidx, first_group, cursor, perm);
    edge_kernel<<<GBLOCKS, 256, 0, stream>>>(erbf, WeT, be, x_hb, vecb, evec, eidx,
                                             perm, group_node, group_valid, G_total,
                                             d_x, d_vec);
}